// Round 6
// baseline (228.562 us; speedup 1.0000x reference)
//
#include <hip/hip_runtime.h>
#include <hip/hip_bf16.h>

// CapsNet dynamic routing — correctness-first. f32 inputs, f32 OUTPUT.
// x: [B=32, N=4096, Din=8] f32, W: [N=4096, C=10, Din=8, D=16] f32
// out: [B=32, C=10, D=16] f32  (reference returns float32!)
//
// Algebra (b0 = 0):
//   iter0 weights = 1/C            -> s0 = (1/C) sum_n u_hat ; v0 = squash(s0)
//   iter1 logits  = u_hat . v0     -> s1 ; v1 = squash(s1)
//   iter2 logits  = u_hat . (v0+v1)-> s2 ; out = squash(s2)

#define BB 32
#define NN 4096
#define CC 10
#define DIN 8
#define DD 16
#define NCHUNKS 32
#define CHUNK (NN / NCHUNKS)   // 128
#define TPB 256

// One block per (b, n-chunk). Thread t: c = t/16, d = t%16 (active iff c < 10).
template<int UNIFORM>
__global__ __launch_bounds__(TPB) void caps_pass(
    const float* __restrict__ xg,    // [B, N, DIN]
    const float* __restrict__ Wg,    // [N, C, DIN, DD]
    const float* __restrict__ vprev, // [B, C, DD]
    float* __restrict__ sAcc)        // [B, C, DD] via atomics
{
    __shared__ float lds_dot[CC * DD];
    __shared__ float lds_logit[CC];

    const int t     = threadIdx.x;
    const int b     = blockIdx.x / NCHUNKS;
    const int chunk = blockIdx.x % NCHUNKS;
    const int c     = t >> 4;
    const int d     = t & 15;
    const bool act  = (c < CC);      // t < 160

    float acc = 0.f;

    for (int jj = 0; jj < CHUNK; ++jj) {
        const int n = chunk * CHUNK + jj;

        float uh = 0.f;
        if (act) {
            // u_hat[b,n,c,d] = sum_i x[b,n,i] * W[n,c,i,d]
            const float* wp = Wg + (((size_t)n * CC + c) * DIN) * DD + d;
            const float* up = xg + ((size_t)b * NN + n) * DIN;
            #pragma unroll
            for (int i = 0; i < DIN; ++i)
                uh = fmaf(up[i], wp[(size_t)i * DD], uh);
        }

        float w;
        if (UNIFORM) {
            w = 1.0f / CC;
        } else {
            if (act) lds_dot[t] = uh * vprev[((size_t)b * CC + c) * DD + d];
            __syncthreads();
            if (t < CC) {
                float L = 0.f;
                #pragma unroll
                for (int dd = 0; dd < DD; ++dd) L += lds_dot[t * DD + dd];
                lds_logit[t] = L;
            }
            __syncthreads();
            float m = lds_logit[0];
            #pragma unroll
            for (int cc = 1; cc < CC; ++cc) m = fmaxf(m, lds_logit[cc]);
            float den = 0.f;
            #pragma unroll
            for (int cc = 0; cc < CC; ++cc) den += __expf(lds_logit[cc] - m);
            w = act ? (__expf(lds_logit[c] - m) / den) : 0.f;
            __syncthreads();   // lds_dot reused next iteration
        }

        if (act) acc = fmaf(w, uh, acc);
    }

    if (act) atomicAdd(&sAcc[((size_t)b * CC + c) * DD + d], acc);
}

// MODE 0: vsum  = squash(s)
// MODE 1: vsum += squash(s)
// MODE 2: outF  = squash(s)   (f32!)
template<int MODE>
__global__ __launch_bounds__(512) void caps_squash(
    const float* __restrict__ sIn,
    float* __restrict__ vsum,
    float* __restrict__ outF)
{
    int r = blockIdx.x * blockDim.x + threadIdx.x;   // row 0..319
    if (r >= BB * CC) return;
    const float* p = sIn + (size_t)r * DD;
    float sv[DD];
    float s2 = 0.f;
    #pragma unroll
    for (int d = 0; d < DD; ++d) { sv[d] = p[d]; s2 = fmaf(sv[d], sv[d], s2); }
    float f = s2 / ((1.f + s2) * sqrtf(s2 + 1e-7f));
    #pragma unroll
    for (int d = 0; d < DD; ++d) {
        float v = f * sv[d];
        int idx = r * DD + d;
        if (MODE == 0) vsum[idx] = v;
        if (MODE == 1) vsum[idx] += v;
        if (MODE == 2) outF[idx] = v;
    }
}

extern "C" void kernel_launch(void* const* d_in, const int* in_sizes, int n_in,
                              void* d_out, int out_size, void* d_ws, size_t ws_size,
                              hipStream_t stream) {
    // Resolve inputs by SIZE (x=1048576 elems, W=5242880 elems).
    const float* x;
    const float* Wt;
    if (in_sizes[0] == BB * NN * DIN) {
        x  = (const float*)d_in[0];
        Wt = (const float*)d_in[1];
    } else {
        Wt = (const float*)d_in[0];
        x  = (const float*)d_in[1];
    }
    float* out = (float*)d_out;   // f32 output — reference returns float32

    float* ws   = (float*)d_ws;
    float* s    = ws;          // 5120 accumulator (re-zeroed per pass)
    float* vsum = ws + 5120;   // 5120 running v0 (+v1)

    const int NBLK = BB * NCHUNKS;  // 1024
    const size_t SBYTES = 5120 * sizeof(float);

    // iter 0: uniform weights (1/C inside pass)
    hipMemsetAsync(s, 0, SBYTES, stream);
    caps_pass<1><<<NBLK, TPB, 0, stream>>>(x, Wt, nullptr, s);
    caps_squash<0><<<1, 512, 0, stream>>>(s, vsum, nullptr);   // vsum = v0
    // iter 1: logits = u_hat . v0
    hipMemsetAsync(s, 0, SBYTES, stream);
    caps_pass<0><<<NBLK, TPB, 0, stream>>>(x, Wt, vsum, s);
    caps_squash<1><<<1, 512, 0, stream>>>(s, vsum, nullptr);   // vsum = v0+v1
    // iter 2: logits = u_hat . (v0+v1)
    hipMemsetAsync(s, 0, SBYTES, stream);
    caps_pass<0><<<NBLK, TPB, 0, stream>>>(x, Wt, vsum, s);
    caps_squash<2><<<1, 512, 0, stream>>>(s, nullptr, out);    // out = v2 (f32)
}